// Round 15
// baseline (117.005 us; speedup 1.0000x reference)
//
#include <hip/hip_runtime.h>

// Encoder layer, MI355X. Pipeline:
//  styles -> prep (fused dcoef + weight-convert + lnorm, XCD-affine)
//  -> QKV GEMM (128x128, BK=64, 2-phase, granule-swizzled LDS, 3 blk/CU)
//  -> flash attn (P-free via K-permutation, LDS-staged K/V, KVBLK=128 in two
//     64-key halves, 32KB LDS, 5 blk/CU, 8 barrier-drains instead of 16)
//  -> out GEMM (128x64, BK=128 dual sub-buffer, swizzled LDS, dual-acc K-halves).

typedef unsigned short u16;
typedef __attribute__((ext_vector_type(8))) short s16x8;   // 8 bf16 (4 VGPRs)
typedef __attribute__((ext_vector_type(4))) float f32x4;
typedef __attribute__((ext_vector_type(4))) unsigned short u16x4;
typedef __attribute__((ext_vector_type(8))) unsigned short u16x8;
typedef __attribute__((ext_vector_type(4))) unsigned int u32x4;

#define WGAIN_C  0.044194173824159216f  // 1/sqrt(512)
// 1/sqrt(32) * log2(e) : folded into Q so attention scores are log2-domain
#define SCALE_L2E (0.17677669529663687f * 1.4426950408889634f)

__device__ __forceinline__ u16 f2bf(float f) {
  union { float f; unsigned u; } v; v.f = f;
  return (u16)((v.u + 0x7FFFu + ((v.u >> 16) & 1u)) >> 16);
}

__device__ __forceinline__ unsigned cvtpk(float lo, float hi) {
  unsigned r;
  asm("v_cvt_pk_bf16_f32 %0, %1, %2" : "=v"(r) : "v"(lo), "v"(hi));
  return r;
}

__device__ __forceinline__ float max3f(float a, float b, float c) {
  return fmaxf(fmaxf(a, b), c);   // clang fuses to v_max3_f32
}

__device__ __forceinline__ void gl_lds16(const u16* g, u16* l) {
  __builtin_amdgcn_global_load_lds(
      (const __attribute__((address_space(1))) unsigned int*)g,
      (__attribute__((address_space(3))) unsigned int*)l, 16, 0, 0);
}

// ---------------- styles = w @ (affine_w.T * WGAIN) + affine_b ----------------
__global__ __launch_bounds__(256) void styles_k(const float* __restrict__ w,
    const float* __restrict__ aw, const float* __restrict__ ab,
    float* __restrict__ styles) {
  int lane = threadIdx.x & 63;
  int col = blockIdx.x * 4 + (threadIdx.x >> 6);   // 0..2047
  const float* awr = aw + (size_t)col * 512 + lane * 8;
  float4 a0 = *(const float4*)awr;
  float4 a1 = *(const float4*)(awr + 4);
  float d[4];
  #pragma unroll
  for (int b = 0; b < 4; b++) {
    const float* wr = w + b * 512 + lane * 8;
    float4 w0 = *(const float4*)wr;
    float4 w1 = *(const float4*)(wr + 4);
    d[b] = a0.x*w0.x + a0.y*w0.y + a0.z*w0.z + a0.w*w0.w
         + a1.x*w1.x + a1.y*w1.y + a1.z*w1.z + a1.w*w1.w;
  }
  #pragma unroll
  for (int m = 1; m < 64; m <<= 1) {
    #pragma unroll
    for (int b = 0; b < 4; b++) d[b] += __shfl_xor(d[b], m);
  }
  if (lane == 0) {
    float abv = ab[col];
    #pragma unroll
    for (int b = 0; b < 4; b++) styles[b * 2048 + col] = d[b] * WGAIN_C + abv;
  }
}

// -------- prep: blocks 0..1279 = dconv (dcoef + bf16 convert), 1280.. = lnorm --------
__global__ __launch_bounds__(256) void prep_k(const float* __restrict__ qw,
    const float* __restrict__ kw, const float* __restrict__ vw,
    const float* __restrict__ ww, const float* __restrict__ uw,
    const float* __restrict__ styles, const float* __restrict__ x,
    float* __restrict__ scl_qkv, float* __restrict__ scl_ou,
    u16* __restrict__ wbq, u16* __restrict__ wcat, u16* __restrict__ xn) {
  __shared__ float red[8];
  if (blockIdx.x < 1280) {
    // ---- dconv ----
    int lane = threadIdx.x & 63;
    int gid = blockIdx.x * 4 + (threadIdx.x >> 6);   // 0..5119
    int mat = gid >> 10;
    int i = gid & 1023;
    const float* W = (mat == 0 ? qw : mat == 1 ? kw : mat == 2 ? vw : mat == 3 ? ww : uw)
                     + (size_t)i * 1024 + lane * 16;
    float4 wv0 = *(const float4*)(W + 0);
    float4 wv1 = *(const float4*)(W + 4);
    float4 wv2 = *(const float4*)(W + 8);
    float4 wv3 = *(const float4*)(W + 12);
    u16* dst = (mat < 3)
        ? wbq + (size_t)mat * 1048576 + (size_t)i * 1024 + lane * 16
        : wcat + (size_t)i * 2048 + (mat == 4 ? 1024 : 0) + lane * 16;
    u16x8 lo = { f2bf(wv0.x), f2bf(wv0.y), f2bf(wv0.z), f2bf(wv0.w),
                 f2bf(wv1.x), f2bf(wv1.y), f2bf(wv1.z), f2bf(wv1.w) };
    u16x8 hi = { f2bf(wv2.x), f2bf(wv2.y), f2bf(wv2.z), f2bf(wv2.w),
                 f2bf(wv3.x), f2bf(wv3.y), f2bf(wv3.z), f2bf(wv3.w) };
    *(u16x8*)dst = lo;
    *(u16x8*)(dst + 8) = hi;
    const float* s = styles + (mat >= 3 ? 1024 : 0) + lane * 16;
    float a[4] = {0.f, 0.f, 0.f, 0.f};
    #pragma unroll
    for (int b = 0; b < 4; b++) {
      const float* sb = s + b * 2048;
      float4 s0 = *(const float4*)(sb + 0);
      float4 s1 = *(const float4*)(sb + 4);
      float4 s2 = *(const float4*)(sb + 8);
      float4 s3 = *(const float4*)(sb + 12);
      float m0, m1, m2, m3;
      m0 = wv0.x*s0.x; m1 = wv0.y*s0.y; m2 = wv0.z*s0.z; m3 = wv0.w*s0.w;
      a[b] += m0*m0 + m1*m1 + m2*m2 + m3*m3;
      m0 = wv1.x*s1.x; m1 = wv1.y*s1.y; m2 = wv1.z*s1.z; m3 = wv1.w*s1.w;
      a[b] += m0*m0 + m1*m1 + m2*m2 + m3*m3;
      m0 = wv2.x*s2.x; m1 = wv2.y*s2.y; m2 = wv2.z*s2.z; m3 = wv2.w*s2.w;
      a[b] += m0*m0 + m1*m1 + m2*m2 + m3*m3;
      m0 = wv3.x*s3.x; m1 = wv3.y*s3.y; m2 = wv3.z*s3.z; m3 = wv3.w*s3.w;
      a[b] += m0*m0 + m1*m1 + m2*m2 + m3*m3;
    }
    #pragma unroll
    for (int m = 1; m < 64; m <<= 1) {
      #pragma unroll
      for (int b = 0; b < 4; b++) a[b] += __shfl_xor(a[b], m);
    }
    if (lane == 0) {
      #pragma unroll
      for (int b = 0; b < 4; b++) {
        float d = rsqrtf(a[b] + 1e-8f);
        if (mat == 2) d *= styles[b * 2048 + 1024 + i];   // fold *s2 into v scale
        if (mat < 3) scl_qkv[mat * 4096 + b * 1024 + i] = d;
        else         scl_ou[(mat - 3) * 4096 + b * 1024 + i] = d;
      }
    }
  } else {
    // ---- lnorm (XCD-affine rows; (bid-1280)%8 == bid%8 since 1280%8==0) ----
    int bid = blockIdx.x - 1280;
    int row = (bid & 7) * 512 + (bid >> 3);   // 0..4095 bijective
    int b = row >> 10;
    int t = threadIdx.x;
    const float* xr = x + (size_t)row * 1024 + t * 4;
    const float* sr = styles + b * 2048 + t * 4;
    float4 xv = *(const float4*)xr;
    float4 sv = *(const float4*)sr;
    float y0 = xv.x*sv.x, y1 = xv.y*sv.y, y2 = xv.z*sv.z, y3 = xv.w*sv.w;
    float sum = y0 + y1 + y2 + y3;
    float ssq = y0*y0 + y1*y1 + y2*y2 + y3*y3;
    #pragma unroll
    for (int m = 1; m < 64; m <<= 1) { sum += __shfl_xor(sum, m); ssq += __shfl_xor(ssq, m); }
    int wave = t >> 6;
    if ((t & 63) == 0) { red[wave] = sum; red[4 + wave] = ssq; }
    __syncthreads();
    sum = red[0] + red[1] + red[2] + red[3];
    ssq = red[4] + red[5] + red[6] + red[7];
    float mu = sum * (1.f / 1024.f);
    float var = ssq * (1.f / 1024.f) - mu * mu;
    float rs = rsqrtf(var + 1e-5f);
    u16x4 o = { f2bf((y0-mu)*rs), f2bf((y1-mu)*rs), f2bf((y2-mu)*rs), f2bf((y3-mu)*rs) };
    *(u16x4*)(xn + (size_t)row * 1024 + t * 4) = o;
  }
}

// ---------------- QKV GEMM: C = xn @ W^T, 128x128 tile, BK=64, XCD m-chunked ----------------
__global__ __launch_bounds__(256) void gemm_qkv_k(const u16* __restrict__ A,
    const u16* __restrict__ Bw, const float* __restrict__ scl_qkv,
    u16* __restrict__ qout, u16* __restrict__ kout, u16* __restrict__ vov,
    u16* __restrict__ vtout) {
  __shared__ u16 Asm[128 * 64];   // [row][granule ^ (row&7)], 16KB
  __shared__ u16 Bsm[128 * 64];
  int tid = threadIdx.x;
  int lane = tid & 63;
  int qi = lane & 15, g = lane >> 4;
  int wave = tid >> 6;
  int wm = wave >> 1, wn = wave & 1;
  int bid = blockIdx.x;                       // 768 blocks
  int xcd = bid & 7, idx = bid >> 3;          // XCD owns 4 m-tiles, streams 24 n-tiles
  int m0 = (xcd * 4 + (idx & 3)) * 128;
  int n0 = (idx >> 2) * 128;
  f32x4 acc[4][4] = {};
  int arow = tid >> 3;                        // 0..31 (rows arow + 32c)
  int acol = ((tid & 7) ^ (arow & 7)) * 8;    // pre-swizzled source column
  const u16* ag = A  + (size_t)(m0 + arow) * 1024 + acol;
  const u16* bg = Bw + (size_t)(n0 + arow) * 1024 + acol;
  u16* adst = Asm + tid * 8;
  u16* bdst = Bsm + tid * 8;
  int qh = qi & 7;
  for (int k0 = 0; k0 < 1024; k0 += 64) {
    #pragma unroll
    for (int c = 0; c < 4; c++) {
      gl_lds16(ag + (size_t)c * 32 * 1024 + k0, adst + c * 2048);
      gl_lds16(bg + (size_t)c * 32 * 1024 + k0, bdst + c * 2048);
    }
    __syncthreads();
    #pragma unroll
    for (int kk = 0; kk < 2; kk++) {
      int sl = ((kk * 4 + g) ^ qh) * 8;
      s16x8 af[4], bf[4];
      #pragma unroll
      for (int i = 0; i < 4; i++)
        af[i] = *(const s16x8*)(Asm + (wm * 64 + i * 16 + qi) * 64 + sl);
      #pragma unroll
      for (int j = 0; j < 4; j++)
        bf[j] = *(const s16x8*)(Bsm + (wn * 64 + j * 16 + qi) * 64 + sl);
      __builtin_amdgcn_s_setprio(1);
      #pragma unroll
      for (int i = 0; i < 4; i++)
        #pragma unroll
        for (int j = 0; j < 4; j++)
          acc[i][j] = __builtin_amdgcn_mfma_f32_16x16x32_bf16(af[i], bf[j], acc[i][j], 0, 0, 0);
      __builtin_amdgcn_s_setprio(0);
    }
    __syncthreads();
  }
  int which = n0 >> 10;           // uniform per block
  int nl0 = n0 & 1023;
  int b = m0 >> 10;
  const float* scl = scl_qkv + which * 4096 + b * 1024;
  u16* outp; int ostride;
  if (which == 0)      { outp = qout; ostride = 1024; }
  else if (which == 1) { outp = kout; ostride = 1024; }
  else                 { outp = vov;  ostride = 2048; }   // v cols of ov buffer
  #pragma unroll
  for (int i = 0; i < 4; i++) {
    int mrow = m0 + wm * 64 + i * 16 + g * 4;
    #pragma unroll
    for (int j = 0; j < 4; j++) {
      int nl = nl0 + wn * 64 + j * 16 + qi;
      float s = scl[nl];
      if (which == 0) s *= SCALE_L2E;   // fold softmax scale + log2e into Q
      u16 b0 = f2bf(acc[i][j][0] * s), b1 = f2bf(acc[i][j][1] * s);
      u16 b2 = f2bf(acc[i][j][2] * s), b3 = f2bf(acc[i][j][3] * s);
      outp[(size_t)(mrow + 0) * ostride + nl] = b0;
      outp[(size_t)(mrow + 1) * ostride + nl] = b1;
      outp[(size_t)(mrow + 2) * ostride + nl] = b2;
      outp[(size_t)(mrow + 3) * ostride + nl] = b3;
      if (which == 2) {
        u16x4 pk = { b0, b1, b2, b3 };
        *(u16x4*)(vtout + (size_t)(b * 1024 + nl) * 1024 + (mrow - b * 1024)) = pk;
      }
    }
  }
}

// ---------------- flash attention (P-free, LDS-staged, KVBLK=128) ----------------
// 4 waves / block, 64 q rows, KVBLK=128 processed as two sequential 64-key
// halves (registers reused), 8 iters -> 8 barrier-drains (vs 16). 32KB LDS ->
// 5 blk/CU. K staged with 128-key permutation pi(klog) = (klog&96) |
// ((klog>>2)&3)*8 | ((klog>>4)&1)*4 | (klog&3) so each lane's packed exp2
// words ARE its PV b-fragment (no P LDS, no cross-lane in steady state).
__global__ __launch_bounds__(256, 5) void attn_k(const u16* __restrict__ q,
    const u16* __restrict__ k, const u16* __restrict__ vt, u16* __restrict__ oout) {
  __shared__ u16 Kl[2][4096];   // 128 keys x 32 d, pair-interleaved swizzle, 8KB
  __shared__ u16 Vl[2][4096];   // 32 d x 128 s, granule swizzle ((d&7)<<1), 8KB
  int tid = threadIdx.x;
  int lane = tid & 63;
  int w = tid >> 6;
  int qi = lane & 15, g = lane >> 4;
  int bid = blockIdx.x;
  int swz = (bid & 7) * 256 + (bid >> 3);   // one head's 16 q-blocks per XCD chunk
  int qblk = swz & 15;
  int bh = swz >> 4;
  int b = bh >> 5, h = bh & 31;
  int q0 = qblk * 64;
  s16x8 qf = *(const s16x8*)(q + (size_t)((b << 10) + q0 + w * 16 + qi) * 1024 + h * 32 + g * 8);
  const u16* kbase = k + (size_t)(b << 10) * 1024 + h * 32;
  const u16* vbase = vt + (size_t)((b << 10) + h * 32) * 1024;
  // K staging: granules gi = tid, tid+256 (512 granules of 16B per tile)
  const u16* ksrcA; const u16* ksrcB;
  {
    int giA = tid, giB = tid + 256;
    int rA = giA >> 3, slA = giA & 7, cpA = slA ^ (rA & 7);
    int klA = 2 * rA + (cpA >> 2), dcA = cpA & 3;
    int kpA = (klA & 96) + ((klA >> 2) & 3) * 8 + ((klA >> 4) & 1) * 4 + (klA & 3);
    ksrcA = kbase + (size_t)kpA * 1024 + dcA * 8;
    int rB = giB >> 3, slB = giB & 7, cpB = slB ^ (rB & 7);
    int klB = 2 * rB + (cpB >> 2), dcB = cpB & 3;
    int kpB = (klB & 96) + ((klB >> 2) & 3) * 8 + ((klB >> 4) & 1) * 4 + (klB & 3);
    ksrcB = kbase + (size_t)kpB * 1024 + dcB * 8;
  }
  // V staging: granule gi -> d = gi>>4 (0..31), slot = gi&15; src s-chunk = slot^((d&7)<<1)
  int vdA = tid >> 4, vsA = (tid & 15) ^ ((vdA & 7) << 1);
  int vdB = (tid + 256) >> 4, vsB = ((tid + 256) & 15) ^ ((vdB & 7) << 1);
  const u16* vsrcA = vbase + (size_t)vdA * 1024 + vsA * 8;
  const u16* vsrcB = vbase + (size_t)vdB * 1024 + vsB * 8;
  float mrun = -1e30f, lsum = 0.f;
  f32x4 o0 = {0.f,0.f,0.f,0.f}, o1 = {0.f,0.f,0.f,0.f};
  const f32x4 zero = {0.f,0.f,0.f,0.f};

  gl_lds16(ksrcA, &Kl[0][0] + tid * 8);
  gl_lds16(ksrcB, &Kl[0][0] + 2048 + tid * 8);
  gl_lds16(vsrcA, &Vl[0][0] + tid * 8);
  gl_lds16(vsrcB, &Vl[0][0] + 2048 + tid * 8);
  __syncthreads();

  for (int it = 0; it < 8; ++it) {
    int nb = it & 1;
    if (it < 7) {
      size_t ko = (size_t)(it + 1) * 128 * 1024;
      int vo = (it + 1) * 128;
      gl_lds16(ksrcA + ko, &Kl[nb ^ 1][0] + tid * 8);
      gl_lds16(ksrcB + ko, &Kl[nb ^ 1][0] + 2048 + tid * 8);
      gl_lds16(vsrcA + vo, &Vl[nb ^ 1][0] + tid * 8);
      gl_lds16(vsrcB + vo, &Vl[nb ^ 1][0] + 2048 + tid * 8);
    }
    int rrb = qi >> 1;
    int ssb = ((((qi & 1) << 2) + g) ^ (qi >> 1)) * 8;
    #pragma unroll
    for (int hh = 0; hh < 2; hh++) {      // two sequential 64-key halves
      f32x4 sa[4];
      __builtin_amdgcn_s_setprio(1);
      #pragma unroll
      for (int kg = 0; kg < 4; kg++) {
        s16x8 kf = *(const s16x8*)(&Kl[nb][0] + (hh * 32 + kg * 8 + rrb) * 64 + ssb);
        sa[kg] = __builtin_amdgcn_mfma_f32_16x16x32_bf16(kf, qf, zero, 0, 0, 0);
      }
      __builtin_amdgcn_s_setprio(0);
      float cm = -1e30f;
      #pragma unroll
      for (int kg = 0; kg < 4; kg++)
        cm = max3f(sa[kg][0], sa[kg][1], max3f(sa[kg][2], sa[kg][3], cm));
      if (__any(cm > mrun + 8.0f)) {      // defer-max
        float t = fmaxf(cm, __shfl_xor(cm, 16));
        t = fmaxf(t, __shfl_xor(t, 32));
        float nm = fmaxf(mrun, t);
        float f = __builtin_amdgcn_exp2f(mrun - nm);
        lsum *= f;
        #pragma unroll
        for (int r = 0; r < 4; r++) { o0[r] *= f; o1[r] *= f; }
        mrun = nm;
      }
      unsigned pwa[4], pwb[4];
      float ps = 0.f;
      #pragma unroll
      for (int kg = 0; kg < 4; kg++) {
        float p0 = __builtin_amdgcn_exp2f(sa[kg][0] - mrun);
        float p1 = __builtin_amdgcn_exp2f(sa[kg][1] - mrun);
        float p2 = __builtin_amdgcn_exp2f(sa[kg][2] - mrun);
        float p3 = __builtin_amdgcn_exp2f(sa[kg][3] - mrun);
        ps += (p0 + p1) + (p2 + p3);
        pwa[kg] = cvtpk(p0, p1);
        pwb[kg] = cvtpk(p2, p3);
      }
      lsum += ps;
      __builtin_amdgcn_s_setprio(1);
      #pragma unroll
      for (int h2 = 0; h2 < 2; h2++) {
        union { u32x4 d; s16x8 v; } pu;
        pu.d = (u32x4){ pwa[2*h2], pwb[2*h2], pwa[2*h2+1], pwb[2*h2+1] };
        int hv = hh * 2 + h2;             // 32-key chunk index within 128
        int voff = ((hv * 4 + g) ^ ((qi & 7) << 1)) * 8;
        s16x8 va0 = *(const s16x8*)(&Vl[nb][0] + qi * 128 + voff);
        s16x8 va1 = *(const s16x8*)(&Vl[nb][0] + (16 + qi) * 128 + voff);
        o0 = __builtin_amdgcn_mfma_f32_16x16x32_bf16(va0, pu.v, o0, 0, 0, 0);
        o1 = __builtin_amdgcn_mfma_f32_16x16x32_bf16(va1, pu.v, o1, 0, 0, 0);
      }
      __builtin_amdgcn_s_setprio(0);
    }
    __syncthreads();
  }
  lsum += __shfl_xor(lsum, 16);
  lsum += __shfl_xor(lsum, 32);
  float inv = 1.f / lsum;
  u16* orow = oout + (size_t)((b << 10) + q0 + w * 16 + qi) * 2048 + h * 32;
  u16x4 w0 = { f2bf(o0[0]*inv), f2bf(o0[1]*inv), f2bf(o0[2]*inv), f2bf(o0[3]*inv) };
  u16x4 w1 = { f2bf(o1[0]*inv), f2bf(o1[1]*inv), f2bf(o1[2]*inv), f2bf(o1[3]*inv) };
  *(u16x4*)(orow + g * 4) = w0;
  *(u16x4*)(orow + 16 + g * 4) = w1;
}

// ---------------- out GEMM: BK=128 (2 proven-swizzle sub-buffers), dual-acc ----------------
// C = (o @ Ww^T)*wd + (v @ Uw^T)*ud; 32 barrier pairs, 64 MFMA/wave per stage.
__global__ __launch_bounds__(256) void gemm_out_k(const u16* __restrict__ A,
    const u16* __restrict__ Bw, const float* __restrict__ scl_ou,
    const float* __restrict__ noi, const float* __restrict__ nst,
    const float* __restrict__ bias, float* __restrict__ out) {
  __shared__ u16 Asm[2][128 * 64];   // [sub-tile][row][granule ^ (row&7)], 32KB
  __shared__ u16 Bsm[2][64 * 64];    // 16KB
  int tid = threadIdx.x;
  int lane = tid & 63;
  int qi = lane & 15, g = lane >> 4;
  int wave = tid >> 6;            // row band
  int bid = blockIdx.x;                       // 512 blocks
  int xcd = bid & 7, idx = bid >> 3;          // XCD owns 4 m-tiles, streams 16 n-tiles
  int m0 = (xcd * 4 + (idx & 3)) * 128;
  int n0 = (idx >> 2) * 64;
  int b = m0 >> 10;
  f32x4 accW[2][4] = {}, accV[2][4] = {};
  int arow = tid >> 3;                        // 0..31
  int acol = ((tid & 7) ^ (arow & 7)) * 8;    // pre-swizzled source column
  const u16* agp = A  + (size_t)(m0 + arow) * 2048 + acol;
  const u16* bgp = Bw + (size_t)(n0 + arow) * 2048 + acol;
  auto kloop = [&](f32x4 (&acc)[2][4], int kbeg) {
    for (int k0 = kbeg; k0 < kbeg + 1024; k0 += 128) {
      #pragma unroll
      for (int s2 = 0; s2 < 2; s2++) {
        u16* adst = &Asm[s2][0] + tid * 8;
        u16* bdst = &Bsm[s2][0] + tid * 8;
        #pragma unroll
        for (int c = 0; c < 4; c++)
          gl_lds16(agp + (size_t)c * 32 * 2048 + k0 + s2 * 64, adst + c * 2048);
        #pragma unroll
        for (int c = 0; c < 2; c++)
          gl_lds16(bgp + (size_t)c * 32 * 2048 + k0 + s2 * 64, bdst + c * 2048);
      }
      __syncthreads();
      #pragma unroll
      for (int s2 = 0; s2 < 2; s2++) {
        #pragma unroll
        for (int h2 = 0; h2 < 2; h2++) {
          int sl = ((h2 * 4 + g) ^ (qi & 7)) * 8;
          s16x8 af[2], bf[4];
          #pragma unroll
          for (int i = 0; i < 2; i++)
            af[i] = *(const s16x8*)(&Asm[s2][0] + (wave * 32 + i * 16 + qi) * 64 + sl);
          #pragma unroll
          for (int j = 0; j < 4; j++)
            bf[j] = *(const s16x8*)(&Bsm[s2][0] + (j * 16 + qi) * 64 + sl);
          __builtin_amdgcn_s_setprio(1);
          #pragma unroll
          for (int i = 0; i < 2; i++)
            #pragma unroll
            for (int j = 0; j < 4; j++)
              acc[i][j] = __builtin_amdgcn_mfma_f32_16x16x32_bf16(af[i], bf[j], acc[i][j], 0, 0, 0);
          __builtin_amdgcn_s_setprio(0);
        }
      }
      __syncthreads();
    }
  };
  kloop(accW, 0);
  kloop(accV, 1024);
  float ns = nst[0];
  #pragma unroll
  for (int i = 0; i < 2; i++) {
    #pragma unroll
    for (int j = 0; j < 4; j++) {
      int n = n0 + j * 16 + qi;
      float bv = bias[n];
      float wd = scl_ou[b * 1024 + n];
      float ud = scl_ou[4096 + b * 1024 + n];
      #pragma unroll
      for (int r = 0; r < 4; r++) {
        int mrow = m0 + wave * 32 + i * 16 + g * 4 + r;
        float v = accW[i][j][r] * wd + accV[i][j][r] * ud + noi[mrow] * ns + bv;
        v = (v >= 0.f) ? v : 0.2f * v;
        v = fminf(fmaxf(v, -256.f), 256.f);
        out[(size_t)mrow * 1024 + n] = v;
      }
    }
  }
}

extern "C" void kernel_launch(void* const* d_in, const int* in_sizes, int n_in,
                              void* d_out, int out_size, void* d_ws, size_t ws_size,
                              hipStream_t stream) {
  const float* x    = (const float*)d_in[0];
  const float* w    = (const float*)d_in[1];
  const float* aw   = (const float*)d_in[2];
  const float* ab   = (const float*)d_in[3];
  const float* qw   = (const float*)d_in[4];
  const float* kw   = (const float*)d_in[5];
  const float* vw   = (const float*)d_in[6];
  const float* wwp  = (const float*)d_in[7];
  const float* uwp  = (const float*)d_in[8];
  const float* bias = (const float*)d_in[9];
  const float* nst  = (const float*)d_in[10];
  const float* noi  = (const float*)d_in[11];
  float* out = (float*)d_out;

  char* ws = (char*)d_ws;
  float* styles  = (float*)ws;  ws += 8192 * 4;           // [4][2048]
  float* scl_qkv = (float*)ws;  ws += 3 * 4096 * 4;       // [3][4][1024]
  float* scl_ou  = (float*)ws;  ws += 2 * 4096 * 4;       // [2][4][1024]
  u16* xn   = (u16*)ws;         ws += (size_t)4194304 * 2; // [4096][1024]
  u16* wbq  = (u16*)ws;         ws += (size_t)3145728 * 2; // [3][1024][1024]
  u16* wcat = (u16*)ws;         ws += (size_t)2097152 * 2; // [1024][2048] = [Ww|Uw]
  u16* qb   = (u16*)ws;         ws += (size_t)4194304 * 2; // [4096][1024]
  u16* kb   = (u16*)ws;         ws += (size_t)4194304 * 2; // [4096][1024]
  u16* vt   = (u16*)ws;         ws += (size_t)4194304 * 2; // [4][1024 hd][1024 s]
  u16* ov   = (u16*)ws;         ws += (size_t)8388608 * 2; // [4096][2048] = [o | v]

  styles_k<<<dim3(512), dim3(256), 0, stream>>>(w, aw, ab, styles);
  prep_k<<<dim3(5376), dim3(256), 0, stream>>>(qw, kw, vw, wwp, uwp, styles, x,
                                               scl_qkv, scl_ou, wbq, wcat, xn);
  gemm_qkv_k<<<dim3(768), dim3(256), 0, stream>>>(xn, wbq, scl_qkv, qb, kb, ov + 1024, vt);
  attn_k<<<dim3(2048), dim3(256), 0, stream>>>(qb, kb, vt, ov);
  gemm_out_k<<<dim3(512), dim3(256), 0, stream>>>(ov, wcat, scl_ou, noi, nst, bias, out);
}

// Round 16
// 116.195 us; speedup vs baseline: 1.0070x; 1.0070x over previous
//
#include <hip/hip_runtime.h>

// Encoder layer, MI355X — FINAL (r13 best config, 116.65 us).
//  styles -> prep (fused dcoef + weight-convert + lnorm, XCD-affine)
//  -> QKV GEMM (128x128, BK=64, 2-phase, granule-swizzled LDS, 3 blk/CU)
//  -> flash attn (P-free via K-permutation, LDS-staged K/V, KVBLK=64, 16KB, 8 blk/CU)
//  -> out GEMM (128x64, BK=128 dual sub-buffer, swizzled LDS, dual-acc K-halves).

typedef unsigned short u16;
typedef __attribute__((ext_vector_type(8))) short s16x8;   // 8 bf16 (4 VGPRs)
typedef __attribute__((ext_vector_type(4))) float f32x4;
typedef __attribute__((ext_vector_type(4))) unsigned short u16x4;
typedef __attribute__((ext_vector_type(8))) unsigned short u16x8;
typedef __attribute__((ext_vector_type(4))) unsigned int u32x4;

#define WGAIN_C  0.044194173824159216f  // 1/sqrt(512)
// 1/sqrt(32) * log2(e) : folded into Q so attention scores are log2-domain
#define SCALE_L2E (0.17677669529663687f * 1.4426950408889634f)

__device__ __forceinline__ u16 f2bf(float f) {
  union { float f; unsigned u; } v; v.f = f;
  return (u16)((v.u + 0x7FFFu + ((v.u >> 16) & 1u)) >> 16);
}

__device__ __forceinline__ unsigned cvtpk(float lo, float hi) {
  unsigned r;
  asm("v_cvt_pk_bf16_f32 %0, %1, %2" : "=v"(r) : "v"(lo), "v"(hi));
  return r;
}

__device__ __forceinline__ float max3f(float a, float b, float c) {
  return fmaxf(fmaxf(a, b), c);   // clang fuses to v_max3_f32
}

__device__ __forceinline__ void gl_lds16(const u16* g, u16* l) {
  __builtin_amdgcn_global_load_lds(
      (const __attribute__((address_space(1))) unsigned int*)g,
      (__attribute__((address_space(3))) unsigned int*)l, 16, 0, 0);
}

// ---------------- styles = w @ (affine_w.T * WGAIN) + affine_b ----------------
__global__ __launch_bounds__(256) void styles_k(const float* __restrict__ w,
    const float* __restrict__ aw, const float* __restrict__ ab,
    float* __restrict__ styles) {
  int lane = threadIdx.x & 63;
  int col = blockIdx.x * 4 + (threadIdx.x >> 6);   // 0..2047
  const float* awr = aw + (size_t)col * 512 + lane * 8;
  float4 a0 = *(const float4*)awr;
  float4 a1 = *(const float4*)(awr + 4);
  float d[4];
  #pragma unroll
  for (int b = 0; b < 4; b++) {
    const float* wr = w + b * 512 + lane * 8;
    float4 w0 = *(const float4*)wr;
    float4 w1 = *(const float4*)(wr + 4);
    d[b] = a0.x*w0.x + a0.y*w0.y + a0.z*w0.z + a0.w*w0.w
         + a1.x*w1.x + a1.y*w1.y + a1.z*w1.z + a1.w*w1.w;
  }
  #pragma unroll
  for (int m = 1; m < 64; m <<= 1) {
    #pragma unroll
    for (int b = 0; b < 4; b++) d[b] += __shfl_xor(d[b], m);
  }
  if (lane == 0) {
    float abv = ab[col];
    #pragma unroll
    for (int b = 0; b < 4; b++) styles[b * 2048 + col] = d[b] * WGAIN_C + abv;
  }
}

// -------- prep: blocks 0..1279 = dconv (dcoef + bf16 convert), 1280.. = lnorm --------
__global__ __launch_bounds__(256) void prep_k(const float* __restrict__ qw,
    const float* __restrict__ kw, const float* __restrict__ vw,
    const float* __restrict__ ww, const float* __restrict__ uw,
    const float* __restrict__ styles, const float* __restrict__ x,
    float* __restrict__ scl_qkv, float* __restrict__ scl_ou,
    u16* __restrict__ wbq, u16* __restrict__ wcat, u16* __restrict__ xn) {
  __shared__ float red[8];
  if (blockIdx.x < 1280) {
    // ---- dconv ----
    int lane = threadIdx.x & 63;
    int gid = blockIdx.x * 4 + (threadIdx.x >> 6);   // 0..5119
    int mat = gid >> 10;
    int i = gid & 1023;
    const float* W = (mat == 0 ? qw : mat == 1 ? kw : mat == 2 ? vw : mat == 3 ? ww : uw)
                     + (size_t)i * 1024 + lane * 16;
    float4 wv0 = *(const float4*)(W + 0);
    float4 wv1 = *(const float4*)(W + 4);
    float4 wv2 = *(const float4*)(W + 8);
    float4 wv3 = *(const float4*)(W + 12);
    u16* dst = (mat < 3)
        ? wbq + (size_t)mat * 1048576 + (size_t)i * 1024 + lane * 16
        : wcat + (size_t)i * 2048 + (mat == 4 ? 1024 : 0) + lane * 16;
    u16x8 lo = { f2bf(wv0.x), f2bf(wv0.y), f2bf(wv0.z), f2bf(wv0.w),
                 f2bf(wv1.x), f2bf(wv1.y), f2bf(wv1.z), f2bf(wv1.w) };
    u16x8 hi = { f2bf(wv2.x), f2bf(wv2.y), f2bf(wv2.z), f2bf(wv2.w),
                 f2bf(wv3.x), f2bf(wv3.y), f2bf(wv3.z), f2bf(wv3.w) };
    *(u16x8*)dst = lo;
    *(u16x8*)(dst + 8) = hi;
    const float* s = styles + (mat >= 3 ? 1024 : 0) + lane * 16;
    float a[4] = {0.f, 0.f, 0.f, 0.f};
    #pragma unroll
    for (int b = 0; b < 4; b++) {
      const float* sb = s + b * 2048;
      float4 s0 = *(const float4*)(sb + 0);
      float4 s1 = *(const float4*)(sb + 4);
      float4 s2 = *(const float4*)(sb + 8);
      float4 s3 = *(const float4*)(sb + 12);
      float m0, m1, m2, m3;
      m0 = wv0.x*s0.x; m1 = wv0.y*s0.y; m2 = wv0.z*s0.z; m3 = wv0.w*s0.w;
      a[b] += m0*m0 + m1*m1 + m2*m2 + m3*m3;
      m0 = wv1.x*s1.x; m1 = wv1.y*s1.y; m2 = wv1.z*s1.z; m3 = wv1.w*s1.w;
      a[b] += m0*m0 + m1*m1 + m2*m2 + m3*m3;
      m0 = wv2.x*s2.x; m1 = wv2.y*s2.y; m2 = wv2.z*s2.z; m3 = wv2.w*s2.w;
      a[b] += m0*m0 + m1*m1 + m2*m2 + m3*m3;
      m0 = wv3.x*s3.x; m1 = wv3.y*s3.y; m2 = wv3.z*s3.z; m3 = wv3.w*s3.w;
      a[b] += m0*m0 + m1*m1 + m2*m2 + m3*m3;
    }
    #pragma unroll
    for (int m = 1; m < 64; m <<= 1) {
      #pragma unroll
      for (int b = 0; b < 4; b++) a[b] += __shfl_xor(a[b], m);
    }
    if (lane == 0) {
      #pragma unroll
      for (int b = 0; b < 4; b++) {
        float d = rsqrtf(a[b] + 1e-8f);
        if (mat == 2) d *= styles[b * 2048 + 1024 + i];   // fold *s2 into v scale
        if (mat < 3) scl_qkv[mat * 4096 + b * 1024 + i] = d;
        else         scl_ou[(mat - 3) * 4096 + b * 1024 + i] = d;
      }
    }
  } else {
    // ---- lnorm (XCD-affine rows; (bid-1280)%8 == bid%8 since 1280%8==0) ----
    int bid = blockIdx.x - 1280;
    int row = (bid & 7) * 512 + (bid >> 3);   // 0..4095 bijective
    int b = row >> 10;
    int t = threadIdx.x;
    const float* xr = x + (size_t)row * 1024 + t * 4;
    const float* sr = styles + b * 2048 + t * 4;
    float4 xv = *(const float4*)xr;
    float4 sv = *(const float4*)sr;
    float y0 = xv.x*sv.x, y1 = xv.y*sv.y, y2 = xv.z*sv.z, y3 = xv.w*sv.w;
    float sum = y0 + y1 + y2 + y3;
    float ssq = y0*y0 + y1*y1 + y2*y2 + y3*y3;
    #pragma unroll
    for (int m = 1; m < 64; m <<= 1) { sum += __shfl_xor(sum, m); ssq += __shfl_xor(ssq, m); }
    int wave = t >> 6;
    if ((t & 63) == 0) { red[wave] = sum; red[4 + wave] = ssq; }
    __syncthreads();
    sum = red[0] + red[1] + red[2] + red[3];
    ssq = red[4] + red[5] + red[6] + red[7];
    float mu = sum * (1.f / 1024.f);
    float var = ssq * (1.f / 1024.f) - mu * mu;
    float rs = rsqrtf(var + 1e-5f);
    u16x4 o = { f2bf((y0-mu)*rs), f2bf((y1-mu)*rs), f2bf((y2-mu)*rs), f2bf((y3-mu)*rs) };
    *(u16x4*)(xn + (size_t)row * 1024 + t * 4) = o;
  }
}

// ---------------- QKV GEMM: C = xn @ W^T, 128x128 tile, BK=64, XCD m-chunked ----------------
__global__ __launch_bounds__(256) void gemm_qkv_k(const u16* __restrict__ A,
    const u16* __restrict__ Bw, const float* __restrict__ scl_qkv,
    u16* __restrict__ qout, u16* __restrict__ kout, u16* __restrict__ vov,
    u16* __restrict__ vtout) {
  __shared__ u16 Asm[128 * 64];   // [row][granule ^ (row&7)], 16KB
  __shared__ u16 Bsm[128 * 64];
  int tid = threadIdx.x;
  int lane = tid & 63;
  int qi = lane & 15, g = lane >> 4;
  int wave = tid >> 6;
  int wm = wave >> 1, wn = wave & 1;
  int bid = blockIdx.x;                       // 768 blocks
  int xcd = bid & 7, idx = bid >> 3;          // XCD owns 4 m-tiles, streams 24 n-tiles
  int m0 = (xcd * 4 + (idx & 3)) * 128;
  int n0 = (idx >> 2) * 128;
  f32x4 acc[4][4] = {};
  int arow = tid >> 3;                        // 0..31 (rows arow + 32c)
  int acol = ((tid & 7) ^ (arow & 7)) * 8;    // pre-swizzled source column
  const u16* ag = A  + (size_t)(m0 + arow) * 1024 + acol;
  const u16* bg = Bw + (size_t)(n0 + arow) * 1024 + acol;
  u16* adst = Asm + tid * 8;
  u16* bdst = Bsm + tid * 8;
  int qh = qi & 7;
  for (int k0 = 0; k0 < 1024; k0 += 64) {
    #pragma unroll
    for (int c = 0; c < 4; c++) {
      gl_lds16(ag + (size_t)c * 32 * 1024 + k0, adst + c * 2048);
      gl_lds16(bg + (size_t)c * 32 * 1024 + k0, bdst + c * 2048);
    }
    __syncthreads();
    #pragma unroll
    for (int kk = 0; kk < 2; kk++) {
      int sl = ((kk * 4 + g) ^ qh) * 8;
      s16x8 af[4], bf[4];
      #pragma unroll
      for (int i = 0; i < 4; i++)
        af[i] = *(const s16x8*)(Asm + (wm * 64 + i * 16 + qi) * 64 + sl);
      #pragma unroll
      for (int j = 0; j < 4; j++)
        bf[j] = *(const s16x8*)(Bsm + (wn * 64 + j * 16 + qi) * 64 + sl);
      __builtin_amdgcn_s_setprio(1);
      #pragma unroll
      for (int i = 0; i < 4; i++)
        #pragma unroll
        for (int j = 0; j < 4; j++)
          acc[i][j] = __builtin_amdgcn_mfma_f32_16x16x32_bf16(af[i], bf[j], acc[i][j], 0, 0, 0);
      __builtin_amdgcn_s_setprio(0);
    }
    __syncthreads();
  }
  int which = n0 >> 10;           // uniform per block
  int nl0 = n0 & 1023;
  int b = m0 >> 10;
  const float* scl = scl_qkv + which * 4096 + b * 1024;
  u16* outp; int ostride;
  if (which == 0)      { outp = qout; ostride = 1024; }
  else if (which == 1) { outp = kout; ostride = 1024; }
  else                 { outp = vov;  ostride = 2048; }   // v cols of ov buffer
  #pragma unroll
  for (int i = 0; i < 4; i++) {
    int mrow = m0 + wm * 64 + i * 16 + g * 4;
    #pragma unroll
    for (int j = 0; j < 4; j++) {
      int nl = nl0 + wn * 64 + j * 16 + qi;
      float s = scl[nl];
      if (which == 0) s *= SCALE_L2E;   // fold softmax scale + log2e into Q
      u16 b0 = f2bf(acc[i][j][0] * s), b1 = f2bf(acc[i][j][1] * s);
      u16 b2 = f2bf(acc[i][j][2] * s), b3 = f2bf(acc[i][j][3] * s);
      outp[(size_t)(mrow + 0) * ostride + nl] = b0;
      outp[(size_t)(mrow + 1) * ostride + nl] = b1;
      outp[(size_t)(mrow + 2) * ostride + nl] = b2;
      outp[(size_t)(mrow + 3) * ostride + nl] = b3;
      if (which == 2) {
        u16x4 pk = { b0, b1, b2, b3 };
        *(u16x4*)(vtout + (size_t)(b * 1024 + nl) * 1024 + (mrow - b * 1024)) = pk;
      }
    }
  }
}

// ---------------- flash attention (P-free, LDS-staged — proven r13 version) ----------------
// 4 waves / block, 64 q rows, KVBLK=64, 16 iters, 16KB LDS -> 8 blocks/CU.
// K staged with key-permutation pi(h*32+u*16+g*4+v)=h*32+g*8+u*4+v so each
// lane's packed exp2 words ARE its PV b-fragment (no P LDS, no cross-lane).
__global__ __launch_bounds__(256, 8) void attn_k(const u16* __restrict__ q,
    const u16* __restrict__ k, const u16* __restrict__ vt, u16* __restrict__ oout) {
  __shared__ u16 Kl[2][2048];
  __shared__ u16 Vl[2][2048];
  int tid = threadIdx.x;
  int lane = tid & 63;
  int w = tid >> 6;
  int qi = lane & 15, g = lane >> 4;
  int bid = blockIdx.x;
  int swz = (bid & 7) * 256 + (bid >> 3);   // one head's 16 q-blocks per XCD chunk
  int qblk = swz & 15;
  int bh = swz >> 4;
  int b = bh >> 5, h = bh & 31;
  int q0 = qblk * 64;
  s16x8 qf = *(const s16x8*)(q + (size_t)((b << 10) + q0 + w * 16 + qi) * 1024 + h * 32 + g * 8);
  const u16* kbase = k + (size_t)(b << 10) * 1024 + h * 32;
  const u16* vbase = vt + (size_t)((b << 10) + h * 32) * 1024;
  int kr_ = tid >> 3, ks_ = tid & 7;
  int kcp = ks_ ^ (kr_ & 7);
  int klog = 2 * kr_ + (kcp >> 2);
  int kdch = kcp & 3;
  int kphys = (klog & 32) + ((klog >> 2) & 3) * 8 + ((klog >> 4) & 1) * 4 + (klog & 3);
  int vd = tid >> 3, vs = tid & 7;
  int vsch = vs ^ (vd & 7);
  const u16* ksrc1 = kbase + (size_t)kphys * 1024 + kdch * 8;
  const u16* vsrc1 = vbase + (size_t)vd * 1024 + vsch * 8;
  float mrun = -1e30f, lsum = 0.f;
  f32x4 o0 = {0.f,0.f,0.f,0.f}, o1 = {0.f,0.f,0.f,0.f};
  const f32x4 zero = {0.f,0.f,0.f,0.f};

  gl_lds16(ksrc1, &Kl[0][0] + tid * 8);
  gl_lds16(vsrc1, &Vl[0][0] + tid * 8);
  __syncthreads();

  for (int it = 0; it < 16; ++it) {
    int nb = it & 1;
    if (it < 15) {
      gl_lds16(ksrc1 + (size_t)(it + 1) * 64 * 1024, &Kl[nb ^ 1][0] + tid * 8);
      gl_lds16(vsrc1 + (it + 1) * 64, &Vl[nb ^ 1][0] + tid * 8);
    }
    f32x4 sa[4];
    __builtin_amdgcn_s_setprio(1);
    #pragma unroll
    for (int kg = 0; kg < 4; kg++) {
      int rr = kg * 8 + (qi >> 1);
      int ss = (((qi & 1) << 2) + g) ^ (qi >> 1);
      s16x8 kf = *(const s16x8*)(&Kl[nb][0] + rr * 64 + ss * 8);
      sa[kg] = __builtin_amdgcn_mfma_f32_16x16x32_bf16(kf, qf, zero, 0, 0, 0);
    }
    __builtin_amdgcn_s_setprio(0);
    float cm = -1e30f;
    #pragma unroll
    for (int kg = 0; kg < 4; kg++)
      cm = max3f(sa[kg][0], sa[kg][1], max3f(sa[kg][2], sa[kg][3], cm));
    if (__any(cm > mrun + 8.0f)) {          // defer-max
      float t = fmaxf(cm, __shfl_xor(cm, 16));
      t = fmaxf(t, __shfl_xor(t, 32));
      float nm = fmaxf(mrun, t);
      float f = __builtin_amdgcn_exp2f(mrun - nm);
      lsum *= f;
      #pragma unroll
      for (int r = 0; r < 4; r++) { o0[r] *= f; o1[r] *= f; }
      mrun = nm;
    }
    unsigned pwa[4], pwb[4];
    float ps = 0.f;
    #pragma unroll
    for (int kg = 0; kg < 4; kg++) {
      float p0 = __builtin_amdgcn_exp2f(sa[kg][0] - mrun);
      float p1 = __builtin_amdgcn_exp2f(sa[kg][1] - mrun);
      float p2 = __builtin_amdgcn_exp2f(sa[kg][2] - mrun);
      float p3 = __builtin_amdgcn_exp2f(sa[kg][3] - mrun);
      ps += (p0 + p1) + (p2 + p3);
      pwa[kg] = cvtpk(p0, p1);
      pwb[kg] = cvtpk(p2, p3);
    }
    lsum += ps;
    __builtin_amdgcn_s_setprio(1);
    #pragma unroll
    for (int h2 = 0; h2 < 2; h2++) {
      union { u32x4 d; s16x8 v; } pu;
      pu.d = (u32x4){ pwa[2*h2], pwb[2*h2], pwa[2*h2+1], pwb[2*h2+1] };
      int vg = ((h2 * 4 + g) ^ (qi & 7)) * 8;
      s16x8 va0 = *(const s16x8*)(&Vl[nb][0] + qi * 64 + vg);
      s16x8 va1 = *(const s16x8*)(&Vl[nb][0] + (16 + qi) * 64 + vg);
      o0 = __builtin_amdgcn_mfma_f32_16x16x32_bf16(va0, pu.v, o0, 0, 0, 0);
      o1 = __builtin_amdgcn_mfma_f32_16x16x32_bf16(va1, pu.v, o1, 0, 0, 0);
    }
    __builtin_amdgcn_s_setprio(0);
    __syncthreads();
  }
  lsum += __shfl_xor(lsum, 16);
  lsum += __shfl_xor(lsum, 32);
  float inv = 1.f / lsum;
  u16* orow = oout + (size_t)((b << 10) + q0 + w * 16 + qi) * 2048 + h * 32;
  u16x4 w0 = { f2bf(o0[0]*inv), f2bf(o0[1]*inv), f2bf(o0[2]*inv), f2bf(o0[3]*inv) };
  u16x4 w1 = { f2bf(o1[0]*inv), f2bf(o1[1]*inv), f2bf(o1[2]*inv), f2bf(o1[3]*inv) };
  *(u16x4*)(orow + g * 4) = w0;
  *(u16x4*)(orow + 16 + g * 4) = w1;
}

// ---------------- out GEMM: BK=128 (2 proven-swizzle sub-buffers), dual-acc ----------------
// C = (o @ Ww^T)*wd + (v @ Uw^T)*ud; 32 barrier pairs, 64 MFMA/wave per stage.
__global__ __launch_bounds__(256) void gemm_out_k(const u16* __restrict__ A,
    const u16* __restrict__ Bw, const float* __restrict__ scl_ou,
    const float* __restrict__ noi, const float* __restrict__ nst,
    const float* __restrict__ bias, float* __restrict__ out) {
  __shared__ u16 Asm[2][128 * 64];   // [sub-tile][row][granule ^ (row&7)], 32KB
  __shared__ u16 Bsm[2][64 * 64];    // 16KB
  int tid = threadIdx.x;
  int lane = tid & 63;
  int qi = lane & 15, g = lane >> 4;
  int wave = tid >> 6;            // row band
  int bid = blockIdx.x;                       // 512 blocks
  int xcd = bid & 7, idx = bid >> 3;          // XCD owns 4 m-tiles, streams 16 n-tiles
  int m0 = (xcd * 4 + (idx & 3)) * 128;
  int n0 = (idx >> 2) * 64;
  int b = m0 >> 10;
  f32x4 accW[2][4] = {}, accV[2][4] = {};
  int arow = tid >> 3;                        // 0..31
  int acol = ((tid & 7) ^ (arow & 7)) * 8;    // pre-swizzled source column
  const u16* agp = A  + (size_t)(m0 + arow) * 2048 + acol;
  const u16* bgp = Bw + (size_t)(n0 + arow) * 2048 + acol;
  auto kloop = [&](f32x4 (&acc)[2][4], int kbeg) {
    for (int k0 = kbeg; k0 < kbeg + 1024; k0 += 128) {
      #pragma unroll
      for (int s2 = 0; s2 < 2; s2++) {
        u16* adst = &Asm[s2][0] + tid * 8;
        u16* bdst = &Bsm[s2][0] + tid * 8;
        #pragma unroll
        for (int c = 0; c < 4; c++)
          gl_lds16(agp + (size_t)c * 32 * 2048 + k0 + s2 * 64, adst + c * 2048);
        #pragma unroll
        for (int c = 0; c < 2; c++)
          gl_lds16(bgp + (size_t)c * 32 * 2048 + k0 + s2 * 64, bdst + c * 2048);
      }
      __syncthreads();
      #pragma unroll
      for (int s2 = 0; s2 < 2; s2++) {
        #pragma unroll
        for (int h2 = 0; h2 < 2; h2++) {
          int sl = ((h2 * 4 + g) ^ (qi & 7)) * 8;
          s16x8 af[2], bf[4];
          #pragma unroll
          for (int i = 0; i < 2; i++)
            af[i] = *(const s16x8*)(&Asm[s2][0] + (wave * 32 + i * 16 + qi) * 64 + sl);
          #pragma unroll
          for (int j = 0; j < 4; j++)
            bf[j] = *(const s16x8*)(&Bsm[s2][0] + (j * 16 + qi) * 64 + sl);
          __builtin_amdgcn_s_setprio(1);
          #pragma unroll
          for (int i = 0; i < 2; i++)
            #pragma unroll
            for (int j = 0; j < 4; j++)
              acc[i][j] = __builtin_amdgcn_mfma_f32_16x16x32_bf16(af[i], bf[j], acc[i][j], 0, 0, 0);
          __builtin_amdgcn_s_setprio(0);
        }
      }
      __syncthreads();
    }
  };
  kloop(accW, 0);
  kloop(accV, 1024);
  float ns = nst[0];
  #pragma unroll
  for (int i = 0; i < 2; i++) {
    #pragma unroll
    for (int j = 0; j < 4; j++) {
      int n = n0 + j * 16 + qi;
      float bv = bias[n];
      float wd = scl_ou[b * 1024 + n];
      float ud = scl_ou[4096 + b * 1024 + n];
      #pragma unroll
      for (int r = 0; r < 4; r++) {
        int mrow = m0 + wave * 32 + i * 16 + g * 4 + r;
        float v = accW[i][j][r] * wd + accV[i][j][r] * ud + noi[mrow] * ns + bv;
        v = (v >= 0.f) ? v : 0.2f * v;
        v = fminf(fmaxf(v, -256.f), 256.f);
        out[(size_t)mrow * 1024 + n] = v;
      }
    }
  }
}

extern "C" void kernel_launch(void* const* d_in, const int* in_sizes, int n_in,
                              void* d_out, int out_size, void* d_ws, size_t ws_size,
                              hipStream_t stream) {
  const float* x    = (const float*)d_in[0];
  const float* w    = (const float*)d_in[1];
  const float* aw   = (const float*)d_in[2];
  const float* ab   = (const float*)d_in[3];
  const float* qw   = (const float*)d_in[4];
  const float* kw   = (const float*)d_in[5];
  const float* vw   = (const float*)d_in[6];
  const float* wwp  = (const float*)d_in[7];
  const float* uwp  = (const float*)d_in[8];
  const float* bias = (const float*)d_in[9];
  const float* nst  = (const float*)d_in[10];
  const float* noi  = (const float*)d_in[11];
  float* out = (float*)d_out;

  char* ws = (char*)d_ws;
  float* styles  = (float*)ws;  ws += 8192 * 4;           // [4][2048]
  float* scl_qkv = (float*)ws;  ws += 3 * 4096 * 4;       // [3][4][1024]
  float* scl_ou  = (float*)ws;  ws += 2 * 4096 * 4;       // [2][4][1024]
  u16* xn   = (u16*)ws;         ws += (size_t)4194304 * 2; // [4096][1024]
  u16* wbq  = (u16*)ws;         ws += (size_t)3145728 * 2; // [3][1024][1024]
  u16* wcat = (u16*)ws;         ws += (size_t)2097152 * 2; // [1024][2048] = [Ww|Uw]
  u16* qb   = (u16*)ws;         ws += (size_t)4194304 * 2; // [4096][1024]
  u16* kb   = (u16*)ws;         ws += (size_t)4194304 * 2; // [4096][1024]
  u16* vt   = (u16*)ws;         ws += (size_t)4194304 * 2; // [4][1024 hd][1024 s]
  u16* ov   = (u16*)ws;         ws += (size_t)8388608 * 2; // [4096][2048] = [o | v]

  styles_k<<<dim3(512), dim3(256), 0, stream>>>(w, aw, ab, styles);
  prep_k<<<dim3(5376), dim3(256), 0, stream>>>(qw, kw, vw, wwp, uwp, styles, x,
                                               scl_qkv, scl_ou, wbq, wcat, xn);
  gemm_qkv_k<<<dim3(768), dim3(256), 0, stream>>>(xn, wbq, scl_qkv, qb, kb, ov + 1024, vt);
  attn_k<<<dim3(2048), dim3(256), 0, stream>>>(qb, kb, vt, ov);
  gemm_out_k<<<dim3(512), dim3(256), 0, stream>>>(ov, wcat, scl_ou, noi, nst, bias, out);
}